// Round 2
// baseline (532.797 us; speedup 1.0000x reference)
//
#include <hip/hip_runtime.h>

typedef _Float16 f16x8 __attribute__((ext_vector_type(8)));
typedef _Float16 f16x4 __attribute__((ext_vector_type(4)));
typedef float f32x4 __attribute__((ext_vector_type(4)));

#define THREADS 512

static __device__ __forceinline__ f32x4 MFMA(f16x8 a, f16x8 b, f32x4 c) {
  return __builtin_amdgcn_mfma_f32_16x16x32_f16(a, b, c, 0, 0, 0);
}

// ---- weight conversion pre-kernel ------------------------------------------
// ws layout:
//   Wb   : 3 x [224][256] f16  (Wq,Wk,Wv; rows >=200 zero)      @ 0       (344064 B)
//   Wcb  : [224][1024] f16     (conv_w flat; rows >=200 zero)   @ 344064  (458752 B)
//   biasp: 3 x [224] f32       (bq,bk,bv padded w/ zeros)       @ 802816  (2688 B)
__global__ void wcvt(const float* __restrict__ Wq, const float* __restrict__ Wk,
                     const float* __restrict__ Wv, const float* __restrict__ cw,
                     const float* __restrict__ bq, const float* __restrict__ bk,
                     const float* __restrict__ bv,
                     _Float16* __restrict__ Wb,
                     _Float16* __restrict__ Wcb,
                     float* __restrict__ biasp) {
  int gt = blockIdx.x * blockDim.x + threadIdx.x;
  int gs = gridDim.x * blockDim.x;
  const int WN = 224 * 256;
  for (int i = gt; i < WN; i += gs) {
    int n = i >> 8;
    Wb[i]          = (n < 200) ? (_Float16)Wq[i] : (_Float16)0.f;
    Wb[WN + i]     = (n < 200) ? (_Float16)Wk[i] : (_Float16)0.f;
    Wb[2 * WN + i] = (n < 200) ? (_Float16)Wv[i] : (_Float16)0.f;
  }
  for (int i = gt; i < 224 * 1024; i += gs) {
    int o = i >> 10;
    Wcb[i] = (o < 200) ? (_Float16)cw[i] : (_Float16)0.f;
  }
  for (int i = gt; i < 224; i += gs) {
    biasp[i]       = (i < 200) ? bq[i] : 0.f;
    biasp[224 + i] = (i < 200) ? bk[i] : 0.f;
    biasp[448 + i] = (i < 200) ? bv[i] : 0.f;
  }
}

// ---- fused per-batch kernel -------------------------------------------------
// LDS map (bytes):
//   Xl  [64][264] f16  @ 0       (33792)
//   Qs  [64][232] f16  @ 33792   (29696)
//   Ks  [64][232] f16  @ 63488   (29696)
//   Vt  [224][72] f16  @ 93184   (32256)   (V transposed: [h][m])
//   Sf  [64][65]  f32  @ 125440  (16640)
//   Sb  [64][72]  f16  @ 142080  (9216)    (softmax result, f16)
//   SA  [64][228] f32  @ 33792   (overlay Qs+Ks; 58368 B, ends 92160 < 93184)
//   Cv  [16][226] f32  @ 125440  (overlay Sf; 14464 B)
// total 151296
#define LDS_BYTES 151296

__global__ __launch_bounds__(THREADS, 2) void fused_kernel(
    const float* __restrict__ x, const _Float16* __restrict__ Wb,
    const _Float16* __restrict__ Wcb, const float* __restrict__ biasp,
    const float* __restrict__ convb, float* __restrict__ out) {
  extern __shared__ char smem[];
  _Float16* Xl = (_Float16*)smem;            // [64][264]
  _Float16* Qs = (_Float16*)(smem + 33792);  // [64][232]
  _Float16* Ks = (_Float16*)(smem + 63488);  // [64][232]
  _Float16* Vt = (_Float16*)(smem + 93184);  // [224][72]
  float* Sf    = (float*)(smem + 125440);    // [64][65]
  _Float16* Sb = (_Float16*)(smem + 142080); // [64][72]
  float* SA    = (float*)(smem + 33792);     // [64][228]
  float* Cv    = (float*)(smem + 125440);    // [16][226]

  const int b = blockIdx.x;
  const int tid = threadIdx.x;
  const int lane = tid & 63;
  const int wave = tid >> 6;
  const int li = lane & 15;
  const int g = lane >> 4;

  // ---- Phase A: load x[b] -> f16 LDS (coalesced float4) ----
  const float* xb = x + (size_t)b * 16384;
  for (int i = tid; i < 4096; i += THREADS) {
    float4 v = ((const float4*)xb)[i];
    int e = i * 4;
    int l = e >> 8, d = e & 255;
    f16x4 h;
    h.x = (_Float16)v.x; h.y = (_Float16)v.y;
    h.z = (_Float16)v.z; h.w = (_Float16)v.w;
    *(f16x4*)(Xl + l * 264 + d) = h;
  }
  __syncthreads();

  // ---- Phase B: Q/K/V projections (relu(x @ W^T + b)), f16 into LDS ----
  for (int u = wave; u < 42; u += 8) {
    int p = u / 14, nt = u % 14;
    int n = nt * 16 + li;
    const _Float16* wrow = Wb + p * (224 * 256) + n * 256 + 8 * g;
    f16x8 bfr[8];
#pragma unroll
    for (int kk = 0; kk < 8; kk++) bfr[kk] = *(const f16x8*)(wrow + kk * 32);
    float bias = biasp[p * 224 + n];
    for (int m = 0; m < 4; m++) {
      f32x4 acc = {0.f, 0.f, 0.f, 0.f};
      const _Float16* arow = Xl + (m * 16 + li) * 264 + 8 * g;
#pragma unroll
      for (int kk = 0; kk < 8; kk++) {
        acc = MFMA(*(const f16x8*)(arow + kk * 32), bfr[kk], acc);
      }
#pragma unroll
      for (int r = 0; r < 4; r++) {
        int row = m * 16 + 4 * g + r;  // l (or m-index for V)
        float v = acc[r] + bias;
        v = v > 0.f ? v : 0.f;
        _Float16 hv = (_Float16)v;
        if (p == 0) Qs[row * 232 + n] = hv;
        else if (p == 1) Ks[row * 232 + n] = hv;
        else Vt[n * 72 + row] = hv;   // V transposed: [h][m]
      }
    }
  }
  __syncthreads();

  // ---- Phase C: scores = q @ k^T  [64][64] f32 ----
  for (int t = wave * 2; t < wave * 2 + 2; t++) {
    int mt = t >> 2, nt = t & 3;
    f32x4 acc = {0.f, 0.f, 0.f, 0.f};
    const _Float16* qrow = Qs + (mt * 16 + li) * 232 + 8 * g;
    const _Float16* krow = Ks + (nt * 16 + li) * 232 + 8 * g;
#pragma unroll
    for (int kk = 0; kk < 7; kk++) {  // K = 224 (padded cols are zero)
      acc = MFMA(*(const f16x8*)(qrow + kk * 32),
                 *(const f16x8*)(krow + kk * 32), acc);
    }
#pragma unroll
    for (int r = 0; r < 4; r++) {
      int row = mt * 16 + 4 * g + r;  // l
      int col = nt * 16 + li;         // m
      Sf[row * 65 + col] = acc[r];
    }
  }
  __syncthreads();

  // ---- Phase D: softmax over axis l (dim=1): per column m ----
  {
    int m = tid >> 3, r = tid & 7;  // 64 cols x 8 threads
    float vals[8];
    float mx = -1e30f;
#pragma unroll
    for (int i = 0; i < 8; i++) {
      float v = Sf[(r + 8 * i) * 65 + m];
      vals[i] = v;
      mx = fmaxf(mx, v);
    }
    mx = fmaxf(mx, __shfl_xor(mx, 1));
    mx = fmaxf(mx, __shfl_xor(mx, 2));
    mx = fmaxf(mx, __shfl_xor(mx, 4));
    float s = 0.f;
#pragma unroll
    for (int i = 0; i < 8; i++) {
      vals[i] = __expf(vals[i] - mx);
      s += vals[i];
    }
    s += __shfl_xor(s, 1);
    s += __shfl_xor(s, 2);
    s += __shfl_xor(s, 4);
    float inv = 1.0f / s;
#pragma unroll
    for (int i = 0; i < 8; i++)
      Sb[(r + 8 * i) * 72 + m] = (_Float16)(vals[i] * inv);
  }
  __syncthreads();

  // ---- Phase E: conv as GEMM [16 x 1024] * [1024 x 224] (into Cv) ----
  for (int nt = wave; nt < 14; nt += 8) {
    int o = nt * 16 + li;
    const _Float16* wrow = Wcb + o * 1024 + 8 * g;
    f32x4 acc = {0.f, 0.f, 0.f, 0.f};
#pragma unroll 4
    for (int kk = 0; kk < 32; kk++) {
      int i1 = kk * 8 + 2 * g;  // j/4 for elems 0..3
      int i2 = i1 + 1;
      union { f16x4 h[2]; f16x8 v; } af;
      af.h[0] = *(const f16x4*)(Xl + (i1 >> 2) * 264 + ((i1 & 3) << 6) + 4 * li);
      af.h[1] = *(const f16x4*)(Xl + (i2 >> 2) * 264 + ((i2 & 3) << 6) + 4 * li);
      acc = MFMA(af.v, *(const f16x8*)(wrow + kk * 32), acc);
    }
#pragma unroll
    for (int r = 0; r < 4; r++) Cv[(4 * g + r) * 226 + o] = acc[r];
  }

  // ---- Phase F: PV: self_att = soft @ v  (into SA, overlays Qs/Ks) ----
  for (int t = wave; t < 56; t += 8) {
    int mt = t / 14, nt = t % 14;
    f32x4 acc = {0.f, 0.f, 0.f, 0.f};
    const _Float16* arow = Sb + (mt * 16 + li) * 72 + 8 * g;
    const _Float16* brow = Vt + (nt * 16 + li) * 72 + 8 * g;
#pragma unroll
    for (int kk = 0; kk < 2; kk++) {  // K = 64 (m)
      acc = MFMA(*(const f16x8*)(arow + kk * 32),
                 *(const f16x8*)(brow + kk * 32), acc);
    }
#pragma unroll
    for (int r = 0; r < 4; r++)
      SA[(mt * 16 + 4 * g + r) * 228 + (nt * 16 + li)] = acc[r];
  }
  __syncthreads();

  // ---- Phase G: pooled self-att + conv + bias -> out ----
  float* ob = out + (size_t)b * 3200;
  for (int t = tid; t < 3200; t += THREADS) {
    int c = t >> 4, s = t & 15;  // c in [0,200), s in [0,16)
    float cv = Cv[s * 226 + c] + convb[c];
    float pool = 0.f;
#pragma unroll
    for (int j = 0; j < 4; j++) {
      int flat = c * 64 + j * 16 + s;  // index into [64,200] flat (l*200+h)
      int l = flat / 200;
      int h = flat - l * 200;
      pool += SA[l * 228 + h];
    }
    ob[t] = cv + 0.25f * pool;
  }
}

// ---- launch -----------------------------------------------------------------
extern "C" void kernel_launch(void* const* d_in, const int* in_sizes, int n_in,
                              void* d_out, int out_size, void* d_ws, size_t ws_size,
                              hipStream_t stream) {
  const float* x  = (const float*)d_in[0];
  const float* Wq = (const float*)d_in[1];
  const float* bq = (const float*)d_in[2];
  const float* Wk = (const float*)d_in[3];
  const float* bk = (const float*)d_in[4];
  const float* Wv = (const float*)d_in[5];
  const float* bv = (const float*)d_in[6];
  const float* cw = (const float*)d_in[7];
  const float* cb = (const float*)d_in[8];

  char* ws = (char*)d_ws;
  _Float16* Wb  = (_Float16*)ws;             // 344064 B
  _Float16* Wcb = (_Float16*)(ws + 344064);  // 458752 B
  float* biasp  = (float*)(ws + 802816);     // 2688 B

  hipLaunchKernelGGL(wcvt, dim3(512), dim3(256), 0, stream,
                     Wq, Wk, Wv, cw, bq, bk, bv, Wb, Wcb, biasp);

  hipFuncSetAttribute((const void*)fused_kernel,
                      hipFuncAttributeMaxDynamicSharedMemorySize, LDS_BYTES);
  hipLaunchKernelGGL(fused_kernel, dim3(4096), dim3(THREADS), LDS_BYTES, stream,
                     x, Wb, Wcb, biasp, cb, (float*)d_out);
}